// Round 6
// baseline (303.026 us; speedup 1.0000x reference)
//
#include <hip/hip_runtime.h>
#include <math.h>

#define N1 4096
#define N2 1024
#define C1 128
#define C2 256
#define CIN 384
#define H 256
#define BATCH 16
#define BN_EPS 1e-5f

typedef __attribute__((ext_vector_type(8))) short bf16x8;
typedef __attribute__((ext_vector_type(4))) float f32x4;

__device__ inline float bf2f(short s) {
    union { unsigned u; float f; } x;
    x.u = ((unsigned)(unsigned short)s) << 16;
    return x.f;
}
__device__ inline short f2bf(float f) {
    union { float f; unsigned u; } x; x.f = f;
    unsigned r = x.u + 0x7fffu + ((x.u >> 16) & 1u);
    return (short)(r >> 16);
}

typedef const __attribute__((address_space(1))) unsigned int guint;
typedef __attribute__((address_space(3))) unsigned int luint;
__device__ inline void gll16(const void* g, void* l) {
    __builtin_amdgcn_global_load_lds((guint*)g, (luint*)l, 16, 0, 0);
}

// ---------------- KNN: exact branchless top-3, packed (idx,w) output ----------------
__global__ __launch_bounds__(256)
void knn_kernel(const float* __restrict__ c1, const float* __restrict__ c2,
                float4* __restrict__ pk) {
    __shared__ __align__(16) float4 sc[N2];
    __shared__ float md[64 * 13];
    __shared__ int   mi[64 * 13];
    const int b = blockIdx.y;
    const float* c2b = c2 + (size_t)b * 3 * N2;
    for (int j = threadIdx.x; j < N2; j += 256) {
        float xx = c2b[j], yy = c2b[N2 + j], zz = c2b[2 * N2 + j];
        sc[j] = make_float4(xx, yy, zz, xx * xx + yy * yy + zz * zz);
    }
    __syncthreads();

    const int t = threadIdx.x;
    const int q = t & 63;
    const int quarter = t >> 6;
    const int n = blockIdx.x * 64 + q;
    const float* c1b = c1 + (size_t)b * 3 * N1;
    const float x = c1b[n], y = c1b[N1 + n], z = c1b[2 * N1 + n];
    const float s1 = x * x + y * y + z * z;

    float d0 = 3.4e38f, d1 = 3.4e38f, d2 = 3.4e38f;
    int i0 = 0, i1 = 0, i2 = 0;
    const int j0 = quarter * 256;
    #pragma unroll 4
    for (int jj = 0; jj < 256; ++jj) {
        const int j = j0 + jj;
        float4 cc = sc[j];
        float dot = x * cc.x + y * cc.y + z * cc.z;
        float d = s1 + cc.w - 2.0f * dot;
        bool c0 = d < d0, c1v = d < d1, c2v = d < d2;
        d2 = c1v ? d1 : (c2v ? d : d2);  i2 = c1v ? i1 : (c2v ? j : i2);
        d1 = c0 ? d0 : (c1v ? d : d1);   i1 = c0 ? i0 : (c1v ? j : i1);
        d0 = c0 ? d  : d0;               i0 = c0 ? j  : i0;
    }
    const int mb = q * 13 + quarter * 3;
    md[mb + 0] = d0; md[mb + 1] = d1; md[mb + 2] = d2;
    mi[mb + 0] = i0; mi[mb + 1] = i1; mi[mb + 2] = i2;
    __syncthreads();

    if (t < 64) {
        float e0 = 3.4e38f, e1 = 3.4e38f, e2 = 3.4e38f;
        int a0 = 0, a1 = 0, a2 = 0;
        #pragma unroll
        for (int r = 0; r < 12; ++r) {
            const int rr = t * 13 + (r / 3) * 3 + (r % 3);
            float d = md[rr]; int j = mi[rr];
            bool c0 = d < e0, c1v = d < e1, c2v = d < e2;
            e2 = c1v ? e1 : (c2v ? d : e2);  a2 = c1v ? a1 : (c2v ? j : a2);
            e1 = c0 ? e0 : (c1v ? d : e1);   a1 = c0 ? a0 : (c1v ? j : a1);
            e0 = c0 ? d  : e0;               a0 = c0 ? j  : a0;
        }
        float r0 = 1.0f / (e0 + 1e-8f);
        float r1 = 1.0f / (e1 + 1e-8f);
        float r2 = 1.0f / (e2 + 1e-8f);
        float rs = r0 + r1 + r2;
        unsigned pack = (unsigned)a0 | ((unsigned)a1 << 10) | ((unsigned)a2 << 20);
        pk[(size_t)b * N1 + n] = make_float4(__uint_as_float(pack), r0 / rs, r1 / rs, r2 / rs);
    }
}

// ---------------- Prep: W [256][K] f32 -> swizzled bf16 [K/8][256][8] ----------------
__global__ __launch_bounds__(256)
void prep_w(const float* __restrict__ W, short* __restrict__ Wsw, int K) {
    const int nkb = K >> 3;
    const int id = blockIdx.x * 256 + threadIdx.x;
    if (id >= 256 * nkb) return;
    const int m = id / nkb, kb = id % nkb;
    const float* src = W + (size_t)m * K + kb * 8;
    bf16x8 v;
    #pragma unroll
    for (int j = 0; j < 8; ++j) v[j] = f2bf(src[j]);
    *(bf16x8*)(Wsw + ((size_t)kb * 256 + m) * 8) = v;
}

// ---------------- Transpose f2 [b][c][j] f32 -> f2t [b][j][c] bf16 ----------------
__global__ __launch_bounds__(256)
void transpose_f2(const float* __restrict__ f2, short* __restrict__ f2t) {
    __shared__ float st[32][33];
    const int j0 = blockIdx.x * 32, c0 = blockIdx.y * 32, b = blockIdx.z;
    const int t = threadIdx.x;
    {
        const int cc = t >> 3, jj = (t & 7) * 4;
        const float* src = f2 + ((size_t)b * C2 + c0 + cc) * N2 + j0 + jj;
        float4 v = *(const float4*)src;
        st[cc][jj + 0] = v.x; st[cc][jj + 1] = v.y;
        st[cc][jj + 2] = v.z; st[cc][jj + 3] = v.w;
    }
    __syncthreads();
    {
        const int j = t >> 3, cb = (t & 7) * 4;
        short4 v = { f2bf(st[cb + 0][j]), f2bf(st[cb + 1][j]),
                     f2bf(st[cb + 2][j]), f2bf(st[cb + 3][j]) };
        *(short4*)(f2t + ((size_t)b * N2 + j0 + j) * C2 + c0 + cb) = v;
    }
}

// ---------------- MFMA GEMM -> Ykc [b][K/8][N1][8] bf16 + BN partials ----------------
// 128(M)x128(N) tile, 256 threads / 4 waves (2x2), wave tile 64x64.
// 1D grid 1024: pair-mates (mh=0/1 sharing a B tile) are 8 apart in dispatch order
// -> same XCD under round-robin -> second B read hits that XCD's L2.
// MODE 0: K=384. B rows [0,128) from f1 (f32 strided); rows [128,384) interp from f2t.
// MODE 1: K=256. B rows from y1kc, BN1+ReLU applied on load.
template<int MODE>
__global__ __launch_bounds__(256, 4)
void gemm_kernel(const short* __restrict__ Wsw,
                 const float* __restrict__ X0, const short* __restrict__ X1,
                 const float4* __restrict__ pk,
                 const float* __restrict__ scale, const float* __restrict__ shift,
                 short* __restrict__ Ykc, float2* __restrict__ P) {
    constexpr int K = (MODE == 0) ? CIN : H;
    constexpr int NT = K / 32;

    __shared__ __align__(16) short A_lds[2][4][128][8];  // 16KB
    __shared__ __align__(16) short B_lds[2][4][128][8];  // 16KB
    __shared__ float sc_s[256], sh_s[256];
    __shared__ float2 pb[128][2];

    const int t = threadIdx.x;
    // decode swizzled 1D grid: d -> (mh, nt, b); pair-mates differ by 8 in d
    const int d = blockIdx.x;
    const int grp = d >> 4, rem = d & 15;
    const int mh = rem >> 3;
    const int pair = grp * 8 + (rem & 7);    // 0..511
    const int nt = pair & 31, b = pair >> 5;
    const int n0 = nt * 128;

    if (MODE == 1 && t < 256) { sc_s[t] = scale[t]; sh_s[t] = shift[t]; }

    const int sn = t & 127;
    const int kh = t >> 7;                   // stages chunks kh and kh+2
    const int lane = t & 63, wv = t >> 6;
    const int wm = wv >> 1, wn = wv & 1;
    const int l16 = lane & 15, lq = lane >> 4;
    const int am_base = wm * 64 + l16;
    const int bn_base = wn * 64 + l16;

    const float* X0b  = (MODE == 0) ? X0 + (size_t)b * C1 * N1 : (const float*)nullptr;
    const short* f2tb = (MODE == 0) ? X1 + (size_t)b * N2 * C2 : (const short*)nullptr;
    const short* y1b  = (MODE == 1) ? X1 + (size_t)b * 32 * N1 * 8 : (const short*)nullptr;

    int gi0 = 0, gi1 = 0, gi2 = 0;
    float gw0 = 0.f, gw1 = 0.f, gw2 = 0.f;
    if (MODE == 0) {
        float4 v = pk[(size_t)b * N1 + n0 + sn];
        unsigned u = __float_as_uint(v.x);
        gi0 = u & 1023; gi1 = (u >> 10) & 1023; gi2 = (u >> 20) & 1023;
        gw0 = v.y; gw1 = v.z; gw2 = v.w;
    }

    f32x4 acc[4][4];
    #pragma unroll
    for (int i = 0; i < 4; ++i)
        #pragma unroll
        for (int j = 0; j < 4; ++j)
            acc[i][j] = (f32x4){0.f, 0.f, 0.f, 0.f};

    auto stageA = [&](int step, int bufi) {
        #pragma unroll
        for (int i = 0; i < 2; ++i) {
            const int c = i * 256 + t;                  // 0..511 chunks of 16B
            const int kb = c >> 7, mm = c & 127;
            const short* g = Wsw + (((size_t)step * 4 + kb) * 256 + mh * 128 + mm) * 8;
            short* l = &A_lds[bufi][0][0][0] + (size_t)c * 8;
            gll16(g, l);
        }
    };

    auto compute = [&](int bufi) {
        bf16x8 a[4], bb[4];
        #pragma unroll
        for (int f = 0; f < 4; ++f) {
            a[f]  = *(const bf16x8*)&A_lds[bufi][lq][am_base + ((f & 1) << 4) + ((f >> 1) << 5)][0];
            bb[f] = *(const bf16x8*)&B_lds[bufi][lq][bn_base + ((f & 1) << 4) + ((f >> 1) << 5)][0];
        }
        #pragma unroll
        for (int i = 0; i < 4; ++i)
            #pragma unroll
            for (int j = 0; j < 4; ++j)
                acc[i][j] = __builtin_amdgcn_mfma_f32_16x16x32_bf16(a[i], bb[j], acc[i][j], 0, 0, 0);
    };

    __syncthreads();   // sc_s ready

    // ---- prologue: stage step 0 into buf 0 ----
    {
        float pf[2][8]; bf16x8 pg[2][3]; bf16x8 py[2];
        #pragma unroll
        for (int ci = 0; ci < 2; ++ci) {
            const int skb = kh + ci * 2;
            if (MODE == 0) {                               // step0 gk<128 always f1
                const float* src = X0b + (size_t)(skb * 8) * N1 + n0 + sn;
                #pragma unroll
                for (int j = 0; j < 8; ++j) pf[ci][j] = src[(size_t)j * N1];
            } else {
                py[ci] = *(const bf16x8*)(y1b + ((size_t)skb * N1 + n0 + sn) * 8);
            }
        }
        stageA(0, 0);
        #pragma unroll
        for (int ci = 0; ci < 2; ++ci) {
            const int skb = kh + ci * 2;
            bf16x8 pv;
            if (MODE == 0) {
                #pragma unroll
                for (int j = 0; j < 8; ++j) pv[j] = f2bf(pf[ci][j]);
            } else {
                const int gk = skb * 8;
                #pragma unroll
                for (int e = 0; e < 8; ++e)
                    pv[e] = f2bf(fmaxf(fmaf(bf2f(py[ci][e]), sc_s[gk + e], sh_s[gk + e]), 0.f));
            }
            *(bf16x8*)&B_lds[0][skb][sn][0] = pv;
        }
        (void)pg;
    }
    __syncthreads();   // buf0 ready (drains gll)

    int buf = 0;
    for (int s = 0; s < NT; ++s) {
        const bool has_next = (s + 1 < NT);
        float pf[2][8]; bf16x8 pg[2][3]; bf16x8 py[2];
        if (has_next) {
            const int sx = s + 1;
            #pragma unroll
            for (int ci = 0; ci < 2; ++ci) {
                const int skb = kh + ci * 2;
                const int gk = sx * 32 + skb * 8;
                if (MODE == 0) {
                    if (gk < C1) {
                        const float* src = X0b + (size_t)gk * N1 + n0 + sn;
                        #pragma unroll
                        for (int j = 0; j < 8; ++j) pf[ci][j] = src[(size_t)j * N1];
                    } else {
                        const int c0 = gk - C1;
                        pg[ci][0] = *(const bf16x8*)(f2tb + (size_t)gi0 * C2 + c0);
                        pg[ci][1] = *(const bf16x8*)(f2tb + (size_t)gi1 * C2 + c0);
                        pg[ci][2] = *(const bf16x8*)(f2tb + (size_t)gi2 * C2 + c0);
                    }
                } else {
                    py[ci] = *(const bf16x8*)(y1b + ((size_t)(sx * 4 + skb) * N1 + n0 + sn) * 8);
                }
            }
            stageA(sx, buf ^ 1);
        }

        compute(buf);

        if (has_next) {
            const int sx = s + 1;
            #pragma unroll
            for (int ci = 0; ci < 2; ++ci) {
                const int skb = kh + ci * 2;
                const int gk = sx * 32 + skb * 8;
                bf16x8 pv;
                if (MODE == 0) {
                    if (gk < C1) {
                        #pragma unroll
                        for (int j = 0; j < 8; ++j) pv[j] = f2bf(pf[ci][j]);
                    } else {
                        #pragma unroll
                        for (int e = 0; e < 8; ++e)
                            pv[e] = f2bf(fmaf(gw2, bf2f(pg[ci][2][e]),
                                         fmaf(gw1, bf2f(pg[ci][1][e]), gw0 * bf2f(pg[ci][0][e]))));
                    }
                } else {
                    #pragma unroll
                    for (int e = 0; e < 8; ++e)
                        pv[e] = f2bf(fmaxf(fmaf(bf2f(py[ci][e]), sc_s[gk + e], sh_s[gk + e]), 0.f));
                }
                *(bf16x8*)&B_lds[buf ^ 1][skb][sn][0] = pv;
            }
        }
        __syncthreads();
        buf ^= 1;
    }

    // ---- epilogue: k-chunked store [kb][n][8] ----
    short* Yb = Ykc + (size_t)b * (K == CIN ? 32 : 32) * 0 + (size_t)b * 32 * N1 * 8;
    #pragma unroll
    for (int i = 0; i < 4; ++i) {
        const int kb = mh * 16 + wm * 8 + i * 2 + (lq >> 1);
        const int kr0 = (lq & 1) * 4;
        #pragma unroll
        for (int j = 0; j < 4; ++j) {
            const int n = n0 + wn * 64 + j * 16 + l16;
            short4 v = { f2bf(acc[i][j][0]), f2bf(acc[i][j][1]),
                         f2bf(acc[i][j][2]), f2bf(acc[i][j][3]) };
            *(short4*)(Yb + ((size_t)kb * N1 + n) * 8 + kr0) = v;
        }
    }

    // ---- BN partials: per-row (sum, sumsq) over this block's 128 cols ----
    #pragma unroll
    for (int i = 0; i < 4; ++i) {
        #pragma unroll
        for (int r = 0; r < 4; ++r) {
            float s = 0.f, qq = 0.f;
            #pragma unroll
            for (int j = 0; j < 4; ++j) {
                float xv = acc[i][j][r];
                s += xv; qq += xv * xv;
            }
            #pragma unroll
            for (int msk = 1; msk < 16; msk <<= 1) {
                s  += __shfl_xor(s, msk);
                qq += __shfl_xor(qq, msk);
            }
            if (l16 == 0)
                pb[wm * 64 + i * 16 + lq * 4 + r][wn] = make_float2(s, qq);
        }
    }
    __syncthreads();
    if (t < 128) {
        float2 a = pb[t][0], c = pb[t][1];
        P[(size_t)(mh * 128 + t) * 512 + b * 32 + nt] = make_float2(a.x + c.x, a.y + c.y);
    }
}

// ---------------- BN reduce: partials [256][512] -> scale/shift ----------------
__global__ __launch_bounds__(256)
void bn_reduce(const float2* __restrict__ P, const float* __restrict__ g,
               const float* __restrict__ be, float* __restrict__ scale,
               float* __restrict__ shift) {
    const int c = blockIdx.x, t = threadIdx.x;
    float2 v0 = P[(size_t)c * 512 + t];
    float2 v1 = P[(size_t)c * 512 + 256 + t];
    float s = v0.x + v1.x, q = v0.y + v1.y;
    __shared__ float ss[256], sq[256];
    ss[t] = s; sq[t] = q;
    __syncthreads();
    for (int o = 128; o > 0; o >>= 1) {
        if (t < o) { ss[t] += ss[t + o]; sq[t] += sq[t + o]; }
        __syncthreads();
    }
    if (t == 0) {
        const float inv = 1.0f / (float)(BATCH * N1);
        float mean = ss[0] * inv;
        float var  = sq[0] * inv - mean * mean;
        float sc = g[c] / sqrtf(var + BN_EPS);
        scale[c] = sc;
        shift[c] = be[c] - mean * sc;
    }
}

// ---------------- Final BN2+ReLU: y2kc -> f32 out (normal layout) ----------------
__global__ __launch_bounds__(256)
void final_bn_relu(const short* __restrict__ y2kc, const float* __restrict__ scale,
                   const float* __restrict__ shift, float* __restrict__ out) {
    const int t = threadIdx.x;
    const int n0 = blockIdx.x * 1024 + t * 4;
    const int kb = blockIdx.y, b = blockIdx.z;
    const short* src = y2kc + ((size_t)(b * 32 + kb) * N1 + n0) * 8;
    bf16x8 v0 = *(const bf16x8*)(src);
    bf16x8 v1 = *(const bf16x8*)(src + 8);
    bf16x8 v2 = *(const bf16x8*)(src + 16);
    bf16x8 v3 = *(const bf16x8*)(src + 24);
    #pragma unroll
    for (int e = 0; e < 8; ++e) {
        const float sc = scale[kb * 8 + e], sh = shift[kb * 8 + e];
        float4 o;
        o.x = fmaxf(fmaf(bf2f(v0[e]), sc, sh), 0.f);
        o.y = fmaxf(fmaf(bf2f(v1[e]), sc, sh), 0.f);
        o.z = fmaxf(fmaf(bf2f(v2[e]), sc, sh), 0.f);
        o.w = fmaxf(fmaf(bf2f(v3[e]), sc, sh), 0.f);
        *(float4*)(out + ((size_t)(b * 256 + kb * 8 + e) * N1) + n0) = o;
    }
}

extern "C" void kernel_launch(void* const* d_in, const int* in_sizes, int n_in,
                              void* d_out, int out_size, void* d_ws, size_t ws_size,
                              hipStream_t stream) {
    const float* c1  = (const float*)d_in[0];
    const float* c2  = (const float*)d_in[1];
    const float* f1  = (const float*)d_in[2];
    const float* f2  = (const float*)d_in[3];
    const float* W1  = (const float*)d_in[4];
    const float* g1  = (const float*)d_in[6];
    const float* be1 = (const float*)d_in[7];
    const float* W2  = (const float*)d_in[8];
    const float* g2  = (const float*)d_in[10];
    const float* be2 = (const float*)d_in[11];
    float* out = (float*)d_out;

    // ws layout (y2kc region hosts f2t/W1s/pk, all dead before gemm2 writes y2kc)
    char* ws = (char*)d_ws;
    short*  y2kc = (short*)ws;                             // [0, 32MB)
    short*  f2t  = (short*)ws;                             // [0, 8MB)
    short*  W1s  = (short*)(ws + (8u << 20));              // 192KB
    float4* pk   = (float4*)(ws + (9u << 20));             // 1MB
    short*  y1kc = (short*)(ws + (32u << 20));             // 32MB
    short*  W2s  = (short*)(ws + (64u << 20));             // 128KB
    float2* P    = (float2*)(ws + (64u << 20) + (256u << 10)); // 1MB
    float* scale1 = (float*)(ws + (64u << 20) + (256u << 10) + (1u << 20));
    float* shift1 = scale1 + 256;
    float* scale2 = shift1 + 256;
    float* shift2 = scale2 + 256;

    prep_w<<<48, 256, 0, stream>>>(W1, W1s, CIN);
    prep_w<<<32, 256, 0, stream>>>(W2, W2s, H);
    transpose_f2<<<dim3(N2 / 32, C2 / 32, BATCH), 256, 0, stream>>>(f2, f2t);
    knn_kernel<<<dim3(N1 / 64, BATCH), 256, 0, stream>>>(c1, c2, pk);

    gemm_kernel<0><<<1024, 256, 0, stream>>>(
        W1s, f1, f2t, pk, nullptr, nullptr, y1kc, P);
    bn_reduce<<<256, 256, 0, stream>>>(P, g1, be1, scale1, shift1);

    gemm_kernel<1><<<1024, 256, 0, stream>>>(
        W2s, nullptr, y1kc, nullptr, scale1, shift1, y2kc, P);
    bn_reduce<<<256, 256, 0, stream>>>(P, g2, be2, scale2, shift2);

    final_bn_relu<<<dim3(N1 / 1024, 32, BATCH), 256, 0, stream>>>(y2kc, scale2, shift2, out);
}

// Round 7
// 154.468 us; speedup vs baseline: 1.9617x; 1.9617x over previous
//
#include <hip/hip_runtime.h>
#include <math.h>

#define N1 4096
#define N2 1024
#define C1 128
#define C2 256
#define CIN 384
#define H 256
#define BATCH 16
#define BN_EPS 1e-5f

typedef __attribute__((ext_vector_type(8))) short bf16x8;
typedef __attribute__((ext_vector_type(4))) float f32x4;

__device__ inline float bf2f(short s) {
    union { unsigned u; float f; } x;
    x.u = ((unsigned)(unsigned short)s) << 16;
    return x.f;
}
__device__ inline short f2bf(float f) {
    union { float f; unsigned u; } x; x.f = f;
    unsigned r = x.u + 0x7fffu + ((x.u >> 16) & 1u);
    return (short)(r >> 16);
}

// ---------------- KNN: exact branchless top-3, packed (idx,w) output ----------------
__global__ __launch_bounds__(256)
void knn_kernel(const float* __restrict__ c1, const float* __restrict__ c2,
                float4* __restrict__ pk) {
    __shared__ __align__(16) float4 sc[N2];
    __shared__ float md[64 * 13];
    __shared__ int   mi[64 * 13];
    const int b = blockIdx.y;
    const float* c2b = c2 + (size_t)b * 3 * N2;
    for (int j = threadIdx.x; j < N2; j += 256) {
        float xx = c2b[j], yy = c2b[N2 + j], zz = c2b[2 * N2 + j];
        sc[j] = make_float4(xx, yy, zz, xx * xx + yy * yy + zz * zz);
    }
    __syncthreads();

    const int t = threadIdx.x;
    const int q = t & 63;
    const int quarter = t >> 6;
    const int n = blockIdx.x * 64 + q;
    const float* c1b = c1 + (size_t)b * 3 * N1;
    const float x = c1b[n], y = c1b[N1 + n], z = c1b[2 * N1 + n];
    const float s1 = x * x + y * y + z * z;

    float d0 = 3.4e38f, d1 = 3.4e38f, d2 = 3.4e38f;
    int i0 = 0, i1 = 0, i2 = 0;
    const int j0 = quarter * 256;
    #pragma unroll 4
    for (int jj = 0; jj < 256; ++jj) {
        const int j = j0 + jj;
        float4 cc = sc[j];
        float dot = x * cc.x + y * cc.y + z * cc.z;
        float d = s1 + cc.w - 2.0f * dot;
        bool c0 = d < d0, c1v = d < d1, c2v = d < d2;
        d2 = c1v ? d1 : (c2v ? d : d2);  i2 = c1v ? i1 : (c2v ? j : i2);
        d1 = c0 ? d0 : (c1v ? d : d1);   i1 = c0 ? i0 : (c1v ? j : i1);
        d0 = c0 ? d  : d0;               i0 = c0 ? j  : i0;
    }
    const int mb = q * 13 + quarter * 3;
    md[mb + 0] = d0; md[mb + 1] = d1; md[mb + 2] = d2;
    mi[mb + 0] = i0; mi[mb + 1] = i1; mi[mb + 2] = i2;
    __syncthreads();

    if (t < 64) {
        float e0 = 3.4e38f, e1 = 3.4e38f, e2 = 3.4e38f;
        int a0 = 0, a1 = 0, a2 = 0;
        #pragma unroll
        for (int r = 0; r < 12; ++r) {
            const int rr = t * 13 + (r / 3) * 3 + (r % 3);
            float d = md[rr]; int j = mi[rr];
            bool c0 = d < e0, c1v = d < e1, c2v = d < e2;
            e2 = c1v ? e1 : (c2v ? d : e2);  a2 = c1v ? a1 : (c2v ? j : a2);
            e1 = c0 ? e0 : (c1v ? d : e1);   a1 = c0 ? a0 : (c1v ? j : a1);
            e0 = c0 ? d  : e0;               a0 = c0 ? j  : a0;
        }
        float r0 = 1.0f / (e0 + 1e-8f);
        float r1 = 1.0f / (e1 + 1e-8f);
        float r2 = 1.0f / (e2 + 1e-8f);
        float rs = r0 + r1 + r2;
        unsigned pack = (unsigned)a0 | ((unsigned)a1 << 10) | ((unsigned)a2 << 20);
        pk[(size_t)b * N1 + n] = make_float4(__uint_as_float(pack), r0 / rs, r1 / rs, r2 / rs);
    }
}

// ---------------- Prep: W [256][K] f32 -> swizzled bf16 [K/8][256][8] ----------------
__global__ __launch_bounds__(256)
void prep_w(const float* __restrict__ W, short* __restrict__ Wsw, int K) {
    const int nkb = K >> 3;
    const int id = blockIdx.x * 256 + threadIdx.x;
    if (id >= 256 * nkb) return;
    const int m = id / nkb, kb = id % nkb;
    const float* src = W + (size_t)m * K + kb * 8;
    bf16x8 v;
    #pragma unroll
    for (int j = 0; j < 8; ++j) v[j] = f2bf(src[j]);
    *(bf16x8*)(Wsw + ((size_t)kb * 256 + m) * 8) = v;
}

// ---------------- Transpose f2 [b][c][j] f32 -> f2t [b][j][c] bf16 ----------------
__global__ __launch_bounds__(256)
void transpose_f2(const float* __restrict__ f2, short* __restrict__ f2t) {
    __shared__ float st[32][33];
    const int j0 = blockIdx.x * 32, c0 = blockIdx.y * 32, b = blockIdx.z;
    const int t = threadIdx.x;
    {
        const int cc = t >> 3, jj = (t & 7) * 4;
        const float* src = f2 + ((size_t)b * C2 + c0 + cc) * N2 + j0 + jj;
        float4 v = *(const float4*)src;
        st[cc][jj + 0] = v.x; st[cc][jj + 1] = v.y;
        st[cc][jj + 2] = v.z; st[cc][jj + 3] = v.w;
    }
    __syncthreads();
    {
        const int j = t >> 3, cb = (t & 7) * 4;
        short4 v = { f2bf(st[cb + 0][j]), f2bf(st[cb + 1][j]),
                     f2bf(st[cb + 2][j]), f2bf(st[cb + 3][j]) };
        *(short4*)(f2t + ((size_t)b * N2 + j0 + j) * C2 + c0 + cb) = v;
    }
}

// ---------------- prep_B1: interp rows in kc layout [b][kb 0..31][n][8] ----------------
__global__ __launch_bounds__(256)
void prep_B1(const short* __restrict__ f2t, const float4* __restrict__ pk,
             short* __restrict__ B1) {
    const int b = blockIdx.y;
    const int n = blockIdx.x * 256 + threadIdx.x;
    float4 v = pk[(size_t)b * N1 + n];
    unsigned u = __float_as_uint(v.x);
    const short* r0 = f2t + ((size_t)b * N2 + (u & 1023u)) * C2;
    const short* r1 = f2t + ((size_t)b * N2 + ((u >> 10) & 1023u)) * C2;
    const short* r2 = f2t + ((size_t)b * N2 + ((u >> 20) & 1023u)) * C2;
    short* ob = B1 + ((size_t)b * 32 * N1 + n) * 8;
    #pragma unroll 4
    for (int kb = 0; kb < 32; ++kb) {
        bf16x8 g0 = *(const bf16x8*)(r0 + kb * 8);
        bf16x8 g1 = *(const bf16x8*)(r1 + kb * 8);
        bf16x8 g2 = *(const bf16x8*)(r2 + kb * 8);
        bf16x8 o;
        #pragma unroll
        for (int e = 0; e < 8; ++e)
            o[e] = f2bf(fmaf(v.w, bf2f(g2[e]), fmaf(v.z, bf2f(g1[e]), v.y * bf2f(g0[e]))));
        *(bf16x8*)(ob + (size_t)kb * N1 * 8) = o;
    }
}

// ---------------- Barrier-free MFMA GEMM: direct fragment loads from global ----------------
// 128(M)x128(N) per block, 256 threads / 4 waves (2m x 2n), wave tile 64x64.
// A frags from Wsw [kb][256][8] (L2-hot), B frags from kc-layout global buffers.
// No LDS staging, no per-step barriers -> each wave pipelines independently.
// 1D grid 1024, pair-swizzled: mh-mates 8 apart in dispatch -> same XCD L2.
// MODE 0: K=384. steps 0..3 B from f1 (f32, strided), steps 4..11 from B1 (kc).
// MODE 1: K=256. B from y1kc (kc), BN1+ReLU applied in-register.
template<int MODE>
__global__ __launch_bounds__(256, 3)
void gemm_kernel(const short* __restrict__ Wsw,
                 const float* __restrict__ f1, const short* __restrict__ Bkc,
                 const float* __restrict__ scale, const float* __restrict__ shift,
                 short* __restrict__ Ykc, float2* __restrict__ P) {
    __shared__ float sc_s[256], sh_s[256];
    __shared__ float2 pb[128][2];

    const int t = threadIdx.x;
    const int d = blockIdx.x;
    const int grp = d >> 4, rem = d & 15;
    const int mh = rem >> 3;
    const int pair = grp * 8 + (rem & 7);    // 0..511
    const int nt = pair & 31, b = pair >> 5;
    const int n0 = nt * 128;

    const int lane = t & 63, wv = t >> 6;
    const int wm = wv >> 1, wn = wv & 1;
    const int l16 = lane & 15, lq = lane >> 4;

    if (MODE == 1) {
        sc_s[t] = scale[t]; sh_s[t] = shift[t];
        __syncthreads();
    }

    const short* Bb = Bkc + (size_t)b * 32 * N1 * 8;
    const short* Abase = Wsw + ((size_t)lq * 256 + mh * 128 + wm * 64 + l16) * 8;
    const int nfr = n0 + wn * 64 + l16;      // fragment column base

    f32x4 acc[4][4];
    #pragma unroll
    for (int i = 0; i < 4; ++i)
        #pragma unroll
        for (int j = 0; j < 4; ++j)
            acc[i][j] = (f32x4){0.f, 0.f, 0.f, 0.f};

    if (MODE == 0) {
        // phase 1: K rows [0,128) from f1 (f32)
        const float* f1b = f1 + (size_t)b * C1 * N1;
        #pragma unroll
        for (int s = 0; s < 4; ++s) {
            bf16x8 a[4], bv[4];
            const short* ap = Abase + (size_t)s * 4 * 256 * 8;
            #pragma unroll
            for (int f = 0; f < 4; ++f) a[f] = *(const bf16x8*)(ap + f * 16 * 8);
            const float* fp = f1b + (size_t)(s * 32 + lq * 8) * N1 + nfr;
            #pragma unroll
            for (int f = 0; f < 4; ++f) {
                #pragma unroll
                for (int e = 0; e < 8; ++e)
                    bv[f][e] = f2bf(fp[(size_t)e * N1 + f * 16]);
            }
            #pragma unroll
            for (int i = 0; i < 4; ++i)
                #pragma unroll
                for (int j = 0; j < 4; ++j)
                    acc[i][j] = __builtin_amdgcn_mfma_f32_16x16x32_bf16(a[i], bv[j], acc[i][j], 0, 0, 0);
        }
        // phase 2: K rows [128,384) from B1 (interp, kc layout)
        #pragma unroll
        for (int s = 4; s < 12; ++s) {
            bf16x8 a[4], bv[4];
            const short* ap = Abase + (size_t)s * 4 * 256 * 8;
            #pragma unroll
            for (int f = 0; f < 4; ++f) a[f] = *(const bf16x8*)(ap + f * 16 * 8);
            const short* bp = Bb + ((size_t)(s * 4 + lq - 16) * N1 + nfr) * 8;
            #pragma unroll
            for (int f = 0; f < 4; ++f) bv[f] = *(const bf16x8*)(bp + f * 16 * 8);
            #pragma unroll
            for (int i = 0; i < 4; ++i)
                #pragma unroll
                for (int j = 0; j < 4; ++j)
                    acc[i][j] = __builtin_amdgcn_mfma_f32_16x16x32_bf16(a[i], bv[j], acc[i][j], 0, 0, 0);
        }
    } else {
        #pragma unroll
        for (int s = 0; s < 8; ++s) {
            bf16x8 a[4], raw[4], bv[4];
            const short* ap = Abase + (size_t)s * 4 * 256 * 8;
            #pragma unroll
            for (int f = 0; f < 4; ++f) a[f] = *(const bf16x8*)(ap + f * 16 * 8);
            const short* bp = Bb + ((size_t)(s * 4 + lq) * N1 + nfr) * 8;
            #pragma unroll
            for (int f = 0; f < 4; ++f) raw[f] = *(const bf16x8*)(bp + f * 16 * 8);
            const int k0 = s * 32 + lq * 8;
            float sck[8], shk[8];
            #pragma unroll
            for (int e = 0; e < 8; ++e) { sck[e] = sc_s[k0 + e]; shk[e] = sh_s[k0 + e]; }
            #pragma unroll
            for (int f = 0; f < 4; ++f)
                #pragma unroll
                for (int e = 0; e < 8; ++e)
                    bv[f][e] = f2bf(fmaxf(fmaf(bf2f(raw[f][e]), sck[e], shk[e]), 0.f));
            #pragma unroll
            for (int i = 0; i < 4; ++i)
                #pragma unroll
                for (int j = 0; j < 4; ++j)
                    acc[i][j] = __builtin_amdgcn_mfma_f32_16x16x32_bf16(a[i], bv[j], acc[i][j], 0, 0, 0);
        }
    }

    // ---- epilogue: k-chunked store [kb][n][8] ----
    short* Yb = Ykc + (size_t)b * 32 * N1 * 8;
    #pragma unroll
    for (int i = 0; i < 4; ++i) {
        const int kb = mh * 16 + wm * 8 + i * 2 + (lq >> 1);
        const int kr0 = (lq & 1) * 4;
        #pragma unroll
        for (int j = 0; j < 4; ++j) {
            const int n = n0 + wn * 64 + j * 16 + l16;
            short4 v = { f2bf(acc[i][j][0]), f2bf(acc[i][j][1]),
                         f2bf(acc[i][j][2]), f2bf(acc[i][j][3]) };
            *(short4*)(Yb + ((size_t)kb * N1 + n) * 8 + kr0) = v;
        }
    }

    // ---- BN partials: per-row (sum, sumsq) over this block's 128 cols ----
    #pragma unroll
    for (int i = 0; i < 4; ++i) {
        #pragma unroll
        for (int r = 0; r < 4; ++r) {
            float s = 0.f, qq = 0.f;
            #pragma unroll
            for (int j = 0; j < 4; ++j) {
                float xv = acc[i][j][r];
                s += xv; qq += xv * xv;
            }
            #pragma unroll
            for (int msk = 1; msk < 16; msk <<= 1) {
                s  += __shfl_xor(s, msk);
                qq += __shfl_xor(qq, msk);
            }
            if (l16 == 0)
                pb[wm * 64 + i * 16 + lq * 4 + r][wn] = make_float2(s, qq);
        }
    }
    __syncthreads();
    if (t < 128) {
        float2 a = pb[t][0], c = pb[t][1];
        P[(size_t)(mh * 128 + t) * 512 + b * 32 + nt] = make_float2(a.x + c.x, a.y + c.y);
    }
}

// ---------------- BN reduce: partials [256][512] -> scale/shift ----------------
__global__ __launch_bounds__(256)
void bn_reduce(const float2* __restrict__ P, const float* __restrict__ g,
               const float* __restrict__ be, float* __restrict__ scale,
               float* __restrict__ shift) {
    const int c = blockIdx.x, t = threadIdx.x;
    float2 v0 = P[(size_t)c * 512 + t];
    float2 v1 = P[(size_t)c * 512 + 256 + t];
    float s = v0.x + v1.x, q = v0.y + v1.y;
    __shared__ float ss[256], sq[256];
    ss[t] = s; sq[t] = q;
    __syncthreads();
    for (int o = 128; o > 0; o >>= 1) {
        if (t < o) { ss[t] += ss[t + o]; sq[t] += sq[t + o]; }
        __syncthreads();
    }
    if (t == 0) {
        const float inv = 1.0f / (float)(BATCH * N1);
        float mean = ss[0] * inv;
        float var  = sq[0] * inv - mean * mean;
        float sc = g[c] / sqrtf(var + BN_EPS);
        scale[c] = sc;
        shift[c] = be[c] - mean * sc;
    }
}

// ---------------- Final BN2+ReLU: y2kc -> f32 out (normal layout) ----------------
__global__ __launch_bounds__(256)
void final_bn_relu(const short* __restrict__ y2kc, const float* __restrict__ scale,
                   const float* __restrict__ shift, float* __restrict__ out) {
    const int t = threadIdx.x;
    const int n0 = blockIdx.x * 1024 + t * 4;
    const int kb = blockIdx.y, b = blockIdx.z;
    const short* src = y2kc + ((size_t)(b * 32 + kb) * N1 + n0) * 8;
    bf16x8 v0 = *(const bf16x8*)(src);
    bf16x8 v1 = *(const bf16x8*)(src + 8);
    bf16x8 v2 = *(const bf16x8*)(src + 16);
    bf16x8 v3 = *(const bf16x8*)(src + 24);
    #pragma unroll
    for (int e = 0; e < 8; ++e) {
        const float sc = scale[kb * 8 + e], sh = shift[kb * 8 + e];
        float4 o;
        o.x = fmaxf(fmaf(bf2f(v0[e]), sc, sh), 0.f);
        o.y = fmaxf(fmaf(bf2f(v1[e]), sc, sh), 0.f);
        o.z = fmaxf(fmaf(bf2f(v2[e]), sc, sh), 0.f);
        o.w = fmaxf(fmaf(bf2f(v3[e]), sc, sh), 0.f);
        *(float4*)(out + ((size_t)(b * 256 + kb * 8 + e) * N1) + n0) = o;
    }
}

extern "C" void kernel_launch(void* const* d_in, const int* in_sizes, int n_in,
                              void* d_out, int out_size, void* d_ws, size_t ws_size,
                              hipStream_t stream) {
    const float* c1  = (const float*)d_in[0];
    const float* c2  = (const float*)d_in[1];
    const float* f1  = (const float*)d_in[2];
    const float* f2  = (const float*)d_in[3];
    const float* W1  = (const float*)d_in[4];
    const float* g1  = (const float*)d_in[6];
    const float* be1 = (const float*)d_in[7];
    const float* W2  = (const float*)d_in[8];
    const float* g2  = (const float*)d_in[10];
    const float* be2 = (const float*)d_in[11];
    float* out = (float*)d_out;

    // ws layout (overlaps exploit kernel ordering):
    // [0,32MB):  B1 (prep_B1 -> gemm1), then y2kc (gemm2 -> final)
    // [32,64MB): f2t (transpose -> prep_B1) in first 8MB, then y1kc (gemm1 -> gemm2)
    // [64MB..):  W1s | W2s | pk | P | scales
    char* ws = (char*)d_ws;
    short*  B1   = (short*)ws;
    short*  y2kc = (short*)ws;
    short*  f2t  = (short*)(ws + (32u << 20));
    short*  y1kc = (short*)(ws + (32u << 20));
    short*  W1s  = (short*)(ws + (64u << 20));
    short*  W2s  = (short*)(ws + (64u << 20) + (256u << 10));
    float4* pk   = (float4*)(ws + (64u << 20) + (512u << 10));
    float2* P    = (float2*)(ws + (64u << 20) + (512u << 10) + (1u << 20));
    float* scale1 = (float*)(ws + (64u << 20) + (512u << 10) + (2u << 20));
    float* shift1 = scale1 + 256;
    float* scale2 = shift1 + 256;
    float* shift2 = scale2 + 256;

    prep_w<<<48, 256, 0, stream>>>(W1, W1s, CIN);
    prep_w<<<32, 256, 0, stream>>>(W2, W2s, H);
    transpose_f2<<<dim3(N2 / 32, C2 / 32, BATCH), 256, 0, stream>>>(f2, f2t);
    knn_kernel<<<dim3(N1 / 64, BATCH), 256, 0, stream>>>(c1, c2, pk);
    prep_B1<<<dim3(N1 / 256, BATCH), 256, 0, stream>>>(f2t, pk, B1);

    gemm_kernel<0><<<1024, 256, 0, stream>>>(
        W1s, f1, B1, nullptr, nullptr, y1kc, P);
    bn_reduce<<<256, 256, 0, stream>>>(P, g1, be1, scale1, shift1);

    gemm_kernel<1><<<1024, 256, 0, stream>>>(
        W2s, nullptr, y1kc, scale1, shift1, y2kc, P);
    bn_reduce<<<256, 256, 0, stream>>>(P, g2, be2, scale2, shift2);

    final_bn_relu<<<dim3(N1 / 1024, 32, BATCH), 256, 0, stream>>>(y2kc, scale2, shift2, out);
}

// Round 8
// 151.436 us; speedup vs baseline: 2.0010x; 1.0200x over previous
//
#include <hip/hip_runtime.h>
#include <math.h>

#define N1 4096
#define N2 1024
#define C1 128
#define C2 256
#define CIN 384
#define H 256
#define BATCH 16
#define BN_EPS 1e-5f

typedef __attribute__((ext_vector_type(8))) short bf16x8;
typedef __attribute__((ext_vector_type(4))) float f32x4;

__device__ inline float bf2f(short s) {
    union { unsigned u; float f; } x;
    x.u = ((unsigned)(unsigned short)s) << 16;
    return x.f;
}
__device__ inline short f2bf(float f) {
    union { float f; unsigned u; } x; x.f = f;
    unsigned r = x.u + 0x7fffu + ((x.u >> 16) & 1u);
    return (short)(r >> 16);
}

// ---------------- KNN: exact top-3 via min/med3 (identical to sorted-insert) ------------
__global__ __launch_bounds__(256)
void knn_kernel(const float* __restrict__ c1, const float* __restrict__ c2,
                float4* __restrict__ pk) {
    __shared__ __align__(16) float4 sc[N2];
    __shared__ float md[64 * 13];
    __shared__ int   mi[64 * 13];
    const int b = blockIdx.y;
    const float* c2b = c2 + (size_t)b * 3 * N2;
    for (int j = threadIdx.x; j < N2; j += 256) {
        float xx = c2b[j], yy = c2b[N2 + j], zz = c2b[2 * N2 + j];
        sc[j] = make_float4(xx, yy, zz, xx * xx + yy * yy + zz * zz);
    }
    __syncthreads();

    const int t = threadIdx.x;
    const int q = t & 63;
    const int quarter = t >> 6;
    const int n = blockIdx.x * 64 + q;
    const float* c1b = c1 + (size_t)b * 3 * N1;
    const float x = c1b[n], y = c1b[N1 + n], z = c1b[2 * N1 + n];
    const float s1 = x * x + y * y + z * z;

    float d0 = 3.4e38f, d1 = 3.4e38f, d2 = 3.4e38f;
    int i0 = 0, i1 = 0, i2 = 0;
    const int j0 = quarter * 256;
    #pragma unroll 8
    for (int jj = 0; jj < 256; ++jj) {
        const int j = j0 + jj;
        float4 cc = sc[j];                       // uniform addr -> LDS broadcast
        float dot = x * cc.x + y * cc.y + z * cc.z;
        float d = s1 + cc.w - 2.0f * dot;        // exact same arithmetic as before (passed)
        // index update (needs compares vs OLD d0/d1/d2)
        bool c0v = d < d0, c1v = d < d1, c2v = d < d2;
        i2 = c1v ? i1 : (c2v ? j : i2);
        i1 = c0v ? i0 : (c1v ? j : i1);
        i0 = c0v ? j  : i0;
        // distance update: sorted-insert == min/med3 network (3 ops)
        d2 = __builtin_amdgcn_fmed3f(d1, d2, d);
        d1 = __builtin_amdgcn_fmed3f(d0, d1, d);
        d0 = fminf(d0, d);
    }
    const int mb = q * 13 + quarter * 3;
    md[mb + 0] = d0; md[mb + 1] = d1; md[mb + 2] = d2;
    mi[mb + 0] = i0; mi[mb + 1] = i1; mi[mb + 2] = i2;
    __syncthreads();

    if (t < 64) {
        float e0 = 3.4e38f, e1 = 3.4e38f, e2 = 3.4e38f;
        int a0 = 0, a1 = 0, a2 = 0;
        #pragma unroll
        for (int r = 0; r < 12; ++r) {
            const int rr = t * 13 + (r / 3) * 3 + (r % 3);
            float d = md[rr]; int j = mi[rr];
            bool c0 = d < e0, c1v = d < e1, c2v = d < e2;
            e2 = c1v ? e1 : (c2v ? d : e2);  a2 = c1v ? a1 : (c2v ? j : a2);
            e1 = c0 ? e0 : (c1v ? d : e1);   a1 = c0 ? a0 : (c1v ? j : a1);
            e0 = c0 ? d  : e0;               a0 = c0 ? j  : a0;
        }
        float r0 = 1.0f / (e0 + 1e-8f);
        float r1 = 1.0f / (e1 + 1e-8f);
        float r2 = 1.0f / (e2 + 1e-8f);
        float rs = r0 + r1 + r2;
        unsigned pack = (unsigned)a0 | ((unsigned)a1 << 10) | ((unsigned)a2 << 20);
        pk[(size_t)b * N1 + n] = make_float4(__uint_as_float(pack), r0 / rs, r1 / rs, r2 / rs);
    }
}

// ---------------- Prep: W [256][K] f32 -> swizzled bf16 [K/8][256][8] ----------------
__global__ __launch_bounds__(256)
void prep_w(const float* __restrict__ W, short* __restrict__ Wsw, int K) {
    const int nkb = K >> 3;
    const int id = blockIdx.x * 256 + threadIdx.x;
    if (id >= 256 * nkb) return;
    const int m = id / nkb, kb = id % nkb;
    const float* src = W + (size_t)m * K + kb * 8;
    bf16x8 v;
    #pragma unroll
    for (int j = 0; j < 8; ++j) v[j] = f2bf(src[j]);
    *(bf16x8*)(Wsw + ((size_t)kb * 256 + m) * 8) = v;
}

// ---------------- Transpose f2 [b][c][j] f32 -> f2t [b][j][c] bf16 ----------------
__global__ __launch_bounds__(256)
void transpose_f2(const float* __restrict__ f2, short* __restrict__ f2t) {
    __shared__ float st[32][33];
    const int j0 = blockIdx.x * 32, c0 = blockIdx.y * 32, b = blockIdx.z;
    const int t = threadIdx.x;
    {
        const int cc = t >> 3, jj = (t & 7) * 4;
        const float* src = f2 + ((size_t)b * C2 + c0 + cc) * N2 + j0 + jj;
        float4 v = *(const float4*)src;
        st[cc][jj + 0] = v.x; st[cc][jj + 1] = v.y;
        st[cc][jj + 2] = v.z; st[cc][jj + 3] = v.w;
    }
    __syncthreads();
    {
        const int j = t >> 3, cb = (t & 7) * 4;
        short4 v = { f2bf(st[cb + 0][j]), f2bf(st[cb + 1][j]),
                     f2bf(st[cb + 2][j]), f2bf(st[cb + 3][j]) };
        *(short4*)(f2t + ((size_t)b * N2 + j0 + j) * C2 + c0 + cb) = v;
    }
}

// ---------------- prep_B1: interp rows in kc layout [b][kb 0..31][n][8] ----------------
__global__ __launch_bounds__(256)
void prep_B1(const short* __restrict__ f2t, const float4* __restrict__ pk,
             short* __restrict__ B1) {
    const int b = blockIdx.y;
    const int n = blockIdx.x * 256 + threadIdx.x;
    float4 v = pk[(size_t)b * N1 + n];
    unsigned u = __float_as_uint(v.x);
    const short* r0 = f2t + ((size_t)b * N2 + (u & 1023u)) * C2;
    const short* r1 = f2t + ((size_t)b * N2 + ((u >> 10) & 1023u)) * C2;
    const short* r2 = f2t + ((size_t)b * N2 + ((u >> 20) & 1023u)) * C2;
    short* ob = B1 + ((size_t)b * 32 * N1 + n) * 8;
    #pragma unroll 4
    for (int kb = 0; kb < 32; ++kb) {
        bf16x8 g0 = *(const bf16x8*)(r0 + kb * 8);
        bf16x8 g1 = *(const bf16x8*)(r1 + kb * 8);
        bf16x8 g2 = *(const bf16x8*)(r2 + kb * 8);
        bf16x8 o;
        #pragma unroll
        for (int e = 0; e < 8; ++e)
            o[e] = f2bf(fmaf(v.w, bf2f(g2[e]), fmaf(v.z, bf2f(g1[e]), v.y * bf2f(g0[e]))));
        *(bf16x8*)(ob + (size_t)kb * N1 * 8) = o;
    }
}

// ---------------- Barrier-free MFMA GEMM: direct fragment loads from global ----------------
// 128(M)x128(N) per block, 256 threads / 4 waves (2m x 2n), wave tile 64x64.
// __launch_bounds__(256,4): hard 128-reg budget (acc 64 AGPR + ~60 VGPR) ->
// 4 blocks/CU, grid 1024 = exactly 4/CU in ONE round (zero ragged tail).
// 1D grid pair-swizzled: mh-mates 8 apart in dispatch -> same XCD L2.
template<int MODE>
__global__ __launch_bounds__(256, 4)
void gemm_kernel(const short* __restrict__ Wsw,
                 const float* __restrict__ f1, const short* __restrict__ Bkc,
                 const float* __restrict__ scale, const float* __restrict__ shift,
                 short* __restrict__ Ykc, float2* __restrict__ P) {
    __shared__ float sc_s[256], sh_s[256];
    __shared__ float2 pb[128][2];

    const int t = threadIdx.x;
    const int d = blockIdx.x;
    const int grp = d >> 4, rem = d & 15;
    const int mh = rem >> 3;
    const int pair = grp * 8 + (rem & 7);    // 0..511
    const int nt = pair & 31, b = pair >> 5;
    const int n0 = nt * 128;

    const int lane = t & 63, wv = t >> 6;
    const int wm = wv >> 1, wn = wv & 1;
    const int l16 = lane & 15, lq = lane >> 4;

    if (MODE == 1) {
        sc_s[t] = scale[t]; sh_s[t] = shift[t];
        __syncthreads();
    }

    const short* Bb = Bkc + (size_t)b * 32 * N1 * 8;
    const short* Abase = Wsw + ((size_t)lq * 256 + mh * 128 + wm * 64 + l16) * 8;
    const int nfr = n0 + wn * 64 + l16;      // fragment column base

    f32x4 acc[4][4];
    #pragma unroll
    for (int i = 0; i < 4; ++i)
        #pragma unroll
        for (int j = 0; j < 4; ++j)
            acc[i][j] = (f32x4){0.f, 0.f, 0.f, 0.f};

    if (MODE == 0) {
        // phase 1: K rows [0,128) from f1 (f32)
        const float* f1b = f1 + (size_t)b * C1 * N1;
        #pragma unroll
        for (int s = 0; s < 4; ++s) {
            bf16x8 a[4], bv[4];
            const short* ap = Abase + (size_t)s * 4 * 256 * 8;
            #pragma unroll
            for (int f = 0; f < 4; ++f) a[f] = *(const bf16x8*)(ap + f * 16 * 8);
            const float* fp = f1b + (size_t)(s * 32 + lq * 8) * N1 + nfr;
            #pragma unroll
            for (int f = 0; f < 4; ++f) {
                #pragma unroll
                for (int e = 0; e < 8; ++e)
                    bv[f][e] = f2bf(fp[(size_t)e * N1 + f * 16]);
            }
            #pragma unroll
            for (int i = 0; i < 4; ++i)
                #pragma unroll
                for (int j = 0; j < 4; ++j)
                    acc[i][j] = __builtin_amdgcn_mfma_f32_16x16x32_bf16(a[i], bv[j], acc[i][j], 0, 0, 0);
        }
        // phase 2: K rows [128,384) from B1 (interp, kc layout)
        #pragma unroll
        for (int s = 4; s < 12; ++s) {
            bf16x8 a[4], bv[4];
            const short* ap = Abase + (size_t)s * 4 * 256 * 8;
            #pragma unroll
            for (int f = 0; f < 4; ++f) a[f] = *(const bf16x8*)(ap + f * 16 * 8);
            const short* bp = Bb + ((size_t)(s * 4 + lq - 16) * N1 + nfr) * 8;
            #pragma unroll
            for (int f = 0; f < 4; ++f) bv[f] = *(const bf16x8*)(bp + f * 16 * 8);
            #pragma unroll
            for (int i = 0; i < 4; ++i)
                #pragma unroll
                for (int j = 0; j < 4; ++j)
                    acc[i][j] = __builtin_amdgcn_mfma_f32_16x16x32_bf16(a[i], bv[j], acc[i][j], 0, 0, 0);
        }
    } else {
        #pragma unroll
        for (int s = 0; s < 8; ++s) {
            bf16x8 a[4], raw[4], bv[4];
            const short* ap = Abase + (size_t)s * 4 * 256 * 8;
            #pragma unroll
            for (int f = 0; f < 4; ++f) a[f] = *(const bf16x8*)(ap + f * 16 * 8);
            const short* bp = Bb + ((size_t)(s * 4 + lq) * N1 + nfr) * 8;
            #pragma unroll
            for (int f = 0; f < 4; ++f) raw[f] = *(const bf16x8*)(bp + f * 16 * 8);
            const int k0 = s * 32 + lq * 8;
            float sck[8], shk[8];
            #pragma unroll
            for (int e = 0; e < 8; ++e) { sck[e] = sc_s[k0 + e]; shk[e] = sh_s[k0 + e]; }
            #pragma unroll
            for (int f = 0; f < 4; ++f)
                #pragma unroll
                for (int e = 0; e < 8; ++e)
                    bv[f][e] = f2bf(fmaxf(fmaf(bf2f(raw[f][e]), sck[e], shk[e]), 0.f));
            #pragma unroll
            for (int i = 0; i < 4; ++i)
                #pragma unroll
                for (int j = 0; j < 4; ++j)
                    acc[i][j] = __builtin_amdgcn_mfma_f32_16x16x32_bf16(a[i], bv[j], acc[i][j], 0, 0, 0);
        }
    }

    // ---- epilogue: k-chunked store [kb][n][8] ----
    short* Yb = Ykc + (size_t)b * 32 * N1 * 8;
    #pragma unroll
    for (int i = 0; i < 4; ++i) {
        const int kb = mh * 16 + wm * 8 + i * 2 + (lq >> 1);
        const int kr0 = (lq & 1) * 4;
        #pragma unroll
        for (int j = 0; j < 4; ++j) {
            const int n = n0 + wn * 64 + j * 16 + l16;
            short4 v = { f2bf(acc[i][j][0]), f2bf(acc[i][j][1]),
                         f2bf(acc[i][j][2]), f2bf(acc[i][j][3]) };
            *(short4*)(Yb + ((size_t)kb * N1 + n) * 8 + kr0) = v;
        }
    }

    // ---- BN partials: per-row (sum, sumsq) over this block's 128 cols ----
    #pragma unroll
    for (int i = 0; i < 4; ++i) {
        #pragma unroll
        for (int r = 0; r < 4; ++r) {
            float s = 0.f, qq = 0.f;
            #pragma unroll
            for (int j = 0; j < 4; ++j) {
                float xv = acc[i][j][r];
                s += xv; qq += xv * xv;
            }
            #pragma unroll
            for (int msk = 1; msk < 16; msk <<= 1) {
                s  += __shfl_xor(s, msk);
                qq += __shfl_xor(qq, msk);
            }
            if (l16 == 0)
                pb[wm * 64 + i * 16 + lq * 4 + r][wn] = make_float2(s, qq);
        }
    }
    __syncthreads();
    if (t < 128) {
        float2 a = pb[t][0], c = pb[t][1];
        P[(size_t)(mh * 128 + t) * 512 + b * 32 + nt] = make_float2(a.x + c.x, a.y + c.y);
    }
}

// ---------------- BN reduce: partials [256][512] -> scale/shift ----------------
__global__ __launch_bounds__(256)
void bn_reduce(const float2* __restrict__ P, const float* __restrict__ g,
               const float* __restrict__ be, float* __restrict__ scale,
               float* __restrict__ shift) {
    const int c = blockIdx.x, t = threadIdx.x;
    float2 v0 = P[(size_t)c * 512 + t];
    float2 v1 = P[(size_t)c * 512 + 256 + t];
    float s = v0.x + v1.x, q = v0.y + v1.y;
    __shared__ float ss[256], sq[256];
    ss[t] = s; sq[t] = q;
    __syncthreads();
    for (int o = 128; o > 0; o >>= 1) {
        if (t < o) { ss[t] += ss[t + o]; sq[t] += sq[t + o]; }
        __syncthreads();
    }
    if (t == 0) {
        const float inv = 1.0f / (float)(BATCH * N1);
        float mean = ss[0] * inv;
        float var  = sq[0] * inv - mean * mean;
        float sc = g[c] / sqrtf(var + BN_EPS);
        scale[c] = sc;
        shift[c] = be[c] - mean * sc;
    }
}

// ---------------- Final BN2+ReLU: y2kc -> f32 out (normal layout) ----------------
__global__ __launch_bounds__(256)
void final_bn_relu(const short* __restrict__ y2kc, const float* __restrict__ scale,
                   const float* __restrict__ shift, float* __restrict__ out) {
    const int t = threadIdx.x;
    const int n0 = blockIdx.x * 1024 + t * 4;
    const int kb = blockIdx.y, b = blockIdx.z;
    const short* src = y2kc + ((size_t)(b * 32 + kb) * N1 + n0) * 8;
    bf16x8 v0 = *(const bf16x8*)(src);
    bf16x8 v1 = *(const bf16x8*)(src + 8);
    bf16x8 v2 = *(const bf16x8*)(src + 16);
    bf16x8 v3 = *(const bf16x8*)(src + 24);
    #pragma unroll
    for (int e = 0; e < 8; ++e) {
        const float sc = scale[kb * 8 + e], sh = shift[kb * 8 + e];
        float4 o;
        o.x = fmaxf(fmaf(bf2f(v0[e]), sc, sh), 0.f);
        o.y = fmaxf(fmaf(bf2f(v1[e]), sc, sh), 0.f);
        o.z = fmaxf(fmaf(bf2f(v2[e]), sc, sh), 0.f);
        o.w = fmaxf(fmaf(bf2f(v3[e]), sc, sh), 0.f);
        *(float4*)(out + ((size_t)(b * 256 + kb * 8 + e) * N1) + n0) = o;
    }
}

extern "C" void kernel_launch(void* const* d_in, const int* in_sizes, int n_in,
                              void* d_out, int out_size, void* d_ws, size_t ws_size,
                              hipStream_t stream) {
    const float* c1  = (const float*)d_in[0];
    const float* c2  = (const float*)d_in[1];
    const float* f1  = (const float*)d_in[2];
    const float* f2  = (const float*)d_in[3];
    const float* W1  = (const float*)d_in[4];
    const float* g1  = (const float*)d_in[6];
    const float* be1 = (const float*)d_in[7];
    const float* W2  = (const float*)d_in[8];
    const float* g2  = (const float*)d_in[10];
    const float* be2 = (const float*)d_in[11];
    float* out = (float*)d_out;

    // ws layout (overlaps exploit kernel ordering):
    // [0,32MB):  B1 (prep_B1 -> gemm1), then y2kc (gemm2 -> final)
    // [32,64MB): f2t (transpose -> prep_B1) in first 8MB, then y1kc (gemm1 -> gemm2)
    // [64MB..):  W1s | W2s | pk | P | scales
    char* ws = (char*)d_ws;
    short*  B1   = (short*)ws;
    short*  y2kc = (short*)ws;
    short*  f2t  = (short*)(ws + (32u << 20));
    short*  y1kc = (short*)(ws + (32u << 20));
    short*  W1s  = (short*)(ws + (64u << 20));
    short*  W2s  = (short*)(ws + (64u << 20) + (256u << 10));
    float4* pk   = (float4*)(ws + (64u << 20) + (512u << 10));
    float2* P    = (float2*)(ws + (64u << 20) + (512u << 10) + (1u << 20));
    float* scale1 = (float*)(ws + (64u << 20) + (512u << 10) + (2u << 20));
    float* shift1 = scale1 + 256;
    float* scale2 = shift1 + 256;
    float* shift2 = scale2 + 256;

    prep_w<<<48, 256, 0, stream>>>(W1, W1s, CIN);
    prep_w<<<32, 256, 0, stream>>>(W2, W2s, H);
    transpose_f2<<<dim3(N2 / 32, C2 / 32, BATCH), 256, 0, stream>>>(f2, f2t);
    knn_kernel<<<dim3(N1 / 64, BATCH), 256, 0, stream>>>(c1, c2, pk);
    prep_B1<<<dim3(N1 / 256, BATCH), 256, 0, stream>>>(f2t, pk, B1);

    gemm_kernel<0><<<1024, 256, 0, stream>>>(
        W1s, f1, B1, nullptr, nullptr, y1kc, P);
    bn_reduce<<<256, 256, 0, stream>>>(P, g1, be1, scale1, shift1);

    gemm_kernel<1><<<1024, 256, 0, stream>>>(
        W2s, nullptr, y1kc, scale1, shift1, y2kc, P);
    bn_reduce<<<256, 256, 0, stream>>>(P, g2, be2, scale2, shift2);

    final_bn_relu<<<dim3(N1 / 1024, 32, BATCH), 256, 0, stream>>>(y2kc, scale2, shift2, out);
}